// Round 9
// baseline (336.701 us; speedup 1.0000x reference)
//
#include <hip/hip_runtime.h>
#include <hip/hip_bf16.h>
#include <hip/hip_fp16.h>
#include <math.h>

#define NN 20000
#define NE 320000
#define SLOT 64  // padded-CSR slots per node; P(deg>64) ~ 1e-18 at mean 16

typedef __attribute__((ext_vector_type(8))) short bf16x8;
typedef __attribute__((ext_vector_type(4))) float f32x4;

__device__ inline float bf2f_lo(uint v) {
    union { uint i; float f; } c; c.i = v << 16; return c.f;
}
__device__ inline float bf2f_hi(uint v) {
    union { uint i; float f; } c; c.i = v & 0xffff0000u; return c.f;
}
__device__ inline ushort f2bf(float f) {
    __hip_bfloat16 h = __float2bfloat16(f);
    return *reinterpret_cast<ushort*>(&h);
}
__device__ inline uint pack2bf(float a, float b) {
    return (uint)f2bf(a) | ((uint)f2bf(b) << 16);
}
__device__ inline float2 h2f2(uint u) {  // 2 packed halves -> 2 floats
    union { uint i; __half2 h; } c; c.i = u;
    return __half22float2(c.h);
}
__device__ inline ushort f2h(float f) {
    __half h = __float2half_rn(f);
    return *reinterpret_cast<ushort*>(&h);
}

__device__ inline float fast_tanh(float x) {
    x = fminf(fmaxf(x, -9.f), 9.f);
    float e = __expf(2.f * x);
    return 1.f - 2.f / (e + 1.f);
}

struct EdgeParams {
    const float *pw0, *pb0, *mu0, *is0;
    const float *pw1, *pb1, *mu1, *is1;
    const float *pw2, *pb2, *mu2, *is2;
};

__device__ inline void layer_w(float p0, float p1, const float* pw, const float* pb,
                               const float* mu, const float* is, float* out4) {
    float u0 = fast_tanh(p0 * pw[0] + p1 * pw[2] + pb[0]);
    float u1 = fast_tanh(p0 * pw[1] + p1 * pw[3] + pb[1]);
#pragma unroll
    for (int k = 0; k < 4; ++k) {
        float d0 = (u0 - mu[k * 2 + 0]) * is[k * 2 + 0];
        float d1 = (u1 - mu[k * 2 + 1]) * is[k * 2 + 1];
        out4[k] = __expf(-0.5f * (d0 * d0 + d1 * d1));
    }
}

// ---- prep: edge records (blocks 0..1249) + weight transpose (1250..1889)
//      + features->bf16 (1890..2514) ----
// Record: 32B = {src, pad, w0(half4=8B), w1, w2} -> ONE cache line per edge scatter.
__global__ void fill_prep(const int* __restrict__ dst, const int* __restrict__ src,
                          const float* __restrict__ pseudo, EdgeParams P,
                          int* __restrict__ cursor, uint* __restrict__ recs,
                          const float* __restrict__ features, ushort* __restrict__ fbf,
                          const float* __restrict__ f0, const float* __restrict__ f1,
                          const float* __restrict__ f2, ushort* __restrict__ w0,
                          ushort* __restrict__ w1, ushort* __restrict__ w2) {
    int bid = blockIdx.x;
    if (bid < 1250) {
        int e = bid * 256 + threadIdx.x;  // 1250*256 == NE exactly
        int n = dst[e];
        int pos = atomicAdd(&cursor[n], 1);
        if (pos < SLOT) {
            size_t slot = (size_t)n * SLOT + pos;
            float2 p = *(const float2*)(pseudo + (size_t)e * 2);  // contiguous read
            float w[4];
            uint pk0x, pk0y, pk1x, pk1y, pk2x, pk2y;
            layer_w(p.x, p.y, P.pw0, P.pb0, P.mu0, P.is0, w);
            pk0x = (uint)f2h(w[0]) | ((uint)f2h(w[1]) << 16);
            pk0y = (uint)f2h(w[2]) | ((uint)f2h(w[3]) << 16);
            layer_w(p.x, p.y, P.pw1, P.pb1, P.mu1, P.is1, w);
            pk1x = (uint)f2h(w[0]) | ((uint)f2h(w[1]) << 16);
            pk1y = (uint)f2h(w[2]) | ((uint)f2h(w[3]) << 16);
            layer_w(p.x, p.y, P.pw2, P.pb2, P.mu2, P.is2, w);
            pk2x = (uint)f2h(w[0]) | ((uint)f2h(w[1]) << 16);
            pk2y = (uint)f2h(w[2]) | ((uint)f2h(w[3]) << 16);
            uint* r = recs + slot * 8;
            *(uint4*)(r + 0) = make_uint4((uint)src[e], 0u, pk0x, pk0y);
            *(uint4*)(r + 4) = make_uint4(pk1x, pk1y, pk2x, pk2y);
        }
    } else if (bid < 1890) {
        int idx = (bid - 1250) * 256 + threadIdx.x;  // 640 blocks cover 163840 exactly
        const float* srcp;
        ushort* dstp;
        int din, KD, li;
        if (idx < 128 * 256) {
            srcp = f0; dstp = w0; din = 64; KD = 256; li = idx;
        } else if (idx < 128 * 256 + 128 * 512) {
            srcp = f1; dstp = w1; din = 128; KD = 512; li = idx - 128 * 256;
        } else {
            srcp = f2; dstp = w2; din = 128; KD = 512; li = idx - 128 * 256 - 128 * 512;
        }
        int n = li / KD;
        int r = li - n * KD;
        int k = r / din;
        int d = r - k * din;
        dstp[li] = f2bf(srcp[d * 512 + k * 128 + n]);
    } else {
        // features f32 -> bf16: 20000*64 = 1.28M elems, 8 per thread, 625 blocks exact
        int idx = (bid - 1890) * 256 + threadIdx.x;  // < 160000
        size_t b8 = (size_t)idx * 8;
        float4 a = *(const float4*)(features + b8);
        float4 b = *(const float4*)(features + b8 + 4);
        uint4 o;
        o.x = pack2bf(a.x, a.y);
        o.y = pack2bf(a.z, a.w);
        o.z = pack2bf(b.x, b.y);
        o.w = pack2bf(b.z, b.w);
        *(uint4*)(fbf + b8) = o;
    }
}

// ---------------- fused layer: 16 waves/block, ONE node per wave, full-wave gather ----------
// Rec reads are wave-uniform -> scalar loads. SEQ=true: probe variant — identical loads,
// chain, bytes; gather row index overridden to a sequential value (dep on rec kept via s>>31).
template <int DIN, bool OUTBF, bool SEQ>
__global__ __launch_bounds__(1024, 2) void layer_fused(
    const ushort* __restrict__ hbf, const int* __restrict__ cursor,
    const uint* __restrict__ recs, int woff,
    const ushort* __restrict__ Bt, const float* __restrict__ bias,
    void* __restrict__ hout) {
    constexpr int KD = 4 * DIN;
    constexpr int PITCH = KD + 8;  // ushorts; 16B-aligned rows
    constexpr int B = 8;
    __shared__ __align__(16) ushort Ts[16 * PITCH];
    int wv = threadIdx.x >> 6, lane = threadIdx.x & 63;
    int l16 = lane & 15, quad = lane >> 4;
    int nb = blockIdx.x * 16;
    int n = nb + wv;

    int deg = __builtin_amdgcn_readfirstlane(cursor[n]);
    deg = deg < SLOT ? deg : SLOT;  // safety clamp
    size_t base = (size_t)n * SLOT;

    if (DIN == 64) {
        float a0 = 0.f, a1 = 0.f, a2 = 0.f, a3 = 0.f;
        for (int i = 0; i < deg; i += B) {
            int s[B]; uint wlo[B], whi[B]; ushort hv[B];
#pragma unroll
            for (int u = 0; u < B; ++u) {
                int ii = i + u;
                bool ok = ii < deg;
                size_t idx = base + (ok ? ii : 0);  // wave-uniform -> s_load
                const uint* r = recs + idx * 8;
                s[u] = (int)r[0];
                wlo[u] = ok ? r[woff] : 0u;
                whi[u] = ok ? r[woff + 1] : 0u;
            }
#pragma unroll
            for (int u = 0; u < B; ++u) {
                int su = SEQ ? (int)(((base >> 2) + i + u) & 16383) + (s[u] >> 31) : s[u];
                hv[u] = hbf[(size_t)su * 64 + lane];
            }
#pragma unroll
            for (int u = 0; u < B; ++u) {
                float2 wa = h2f2(wlo[u]);
                float2 wb = h2f2(whi[u]);
                float f = bf2f_lo((uint)hv[u]);
                a0 += wa.x * f;
                a1 += wa.y * f;
                a2 += wb.x * f;
                a3 += wb.y * f;
            }
        }
        Ts[wv * PITCH + 0 * 64 + lane] = f2bf(a0);
        Ts[wv * PITCH + 1 * 64 + lane] = f2bf(a1);
        Ts[wv * PITCH + 2 * 64 + lane] = f2bf(a2);
        Ts[wv * PITCH + 3 * 64 + lane] = f2bf(a3);
    } else {
        float a00 = 0.f, a01 = 0.f, a10 = 0.f, a11 = 0.f;
        float a20 = 0.f, a21 = 0.f, a30 = 0.f, a31 = 0.f;
        for (int i = 0; i < deg; i += B) {
            int s[B]; uint wlo[B], whi[B]; uint v[B];
#pragma unroll
            for (int u = 0; u < B; ++u) {
                int ii = i + u;
                bool ok = ii < deg;
                size_t idx = base + (ok ? ii : 0);  // wave-uniform -> s_load
                const uint* r = recs + idx * 8;
                s[u] = (int)r[0];
                wlo[u] = ok ? r[woff] : 0u;
                whi[u] = ok ? r[woff + 1] : 0u;
            }
#pragma unroll
            for (int u = 0; u < B; ++u) {
                int su = SEQ ? (int)(((base >> 2) + i + u) & 16383) + (s[u] >> 31) : s[u];
                v[u] = *(const uint*)(hbf + (size_t)su * 128 + lane * 2);
            }
#pragma unroll
            for (int u = 0; u < B; ++u) {
                float2 wa = h2f2(wlo[u]);
                float2 wb = h2f2(whi[u]);
                float lo = bf2f_lo(v[u]), hi = bf2f_hi(v[u]);
                a00 += wa.x * lo; a01 += wa.x * hi;
                a10 += wa.y * lo; a11 += wa.y * hi;
                a20 += wb.x * lo; a21 += wb.x * hi;
                a30 += wb.y * lo; a31 += wb.y * hi;
            }
        }
        ushort2 p;
        p.x = f2bf(a00); p.y = f2bf(a01);
        *(ushort2*)(Ts + wv * PITCH + 0 * 128 + lane * 2) = p;
        p.x = f2bf(a10); p.y = f2bf(a11);
        *(ushort2*)(Ts + wv * PITCH + 1 * 128 + lane * 2) = p;
        p.x = f2bf(a20); p.y = f2bf(a21);
        *(ushort2*)(Ts + wv * PITCH + 2 * 128 + lane * 2) = p;
        p.x = f2bf(a30); p.y = f2bf(a31);
        *(ushort2*)(Ts + wv * PITCH + 3 * 128 + lane * 2) = p;
    }
    __syncthreads();

    // ---- GEMM phase: waves 0..7, each 16 rows x 16 cols ----
    if (wv < 8) {
        int c0 = wv * 16;
        f32x4 acc = (f32x4){0.f, 0.f, 0.f, 0.f};
#pragma unroll 4
        for (int k0 = 0; k0 < KD; k0 += 32) {
            bf16x8 af = *(const bf16x8*)(Ts + l16 * PITCH + k0 + quad * 8);
            bf16x8 bfr = *(const bf16x8*)(Bt + (size_t)(c0 + l16) * KD + k0 + quad * 8);
            acc = __builtin_amdgcn_mfma_f32_16x16x32_bf16(af, bfr, acc, 0, 0, 0);
        }
        int gn = c0 + l16;
        float bv = bias[gn];
#pragma unroll
        for (int i = 0; i < 4; ++i) {
            int gm = nb + quad * 4 + i;
            float val = acc[i] + bv;
            if (OUTBF)
                ((ushort*)hout)[(size_t)gm * 128 + gn] = f2bf(val);
            else
                ((float*)hout)[(size_t)gm * 128 + gn] = val;
        }
    }
}

extern "C" void kernel_launch(void* const* d_in, const int* in_sizes, int n_in,
                              void* d_out, int out_size, void* d_ws, size_t ws_size,
                              hipStream_t stream) {
    const float* features = (const float*)d_in[0];
    const float* pseudo = (const float*)d_in[1];
    const int* src = (const int*)d_in[2];
    const int* dst = (const int*)d_in[3];
    const float* fc_w[3] = {(const float*)d_in[4], (const float*)d_in[10], (const float*)d_in[16]};
    const float* mu[3] = {(const float*)d_in[5], (const float*)d_in[11], (const float*)d_in[17]};
    const float* isg[3] = {(const float*)d_in[6], (const float*)d_in[12], (const float*)d_in[18]};
    const float* bias[3] = {(const float*)d_in[7], (const float*)d_in[13], (const float*)d_in[19]};
    const float* pw[3] = {(const float*)d_in[8], (const float*)d_in[14], (const float*)d_in[20]};
    const float* pb[3] = {(const float*)d_in[9], (const float*)d_in[15], (const float*)d_in[21]};

    char* ws = (char*)d_ws;
    auto alloc = [&](size_t bytes) -> void* {
        void* p = (void*)ws;
        ws += (bytes + 255) & ~(size_t)255;
        return p;
    };
    int* cursor = (int*)alloc((size_t)NN * 4);
    uint* recs = (uint*)alloc((size_t)NN * SLOT * 32);   // 32B record per slot
    ushort* fbf = (ushort*)alloc((size_t)NN * 64 * 2);   // features in bf16
    ushort* w2t_0 = (ushort*)alloc((size_t)128 * 256 * 2);
    ushort* w2t_1 = (ushort*)alloc((size_t)128 * 512 * 2);
    ushort* w2t_2 = (ushort*)alloc((size_t)128 * 512 * 2);
    ushort* h1 = (ushort*)alloc((size_t)NN * 128 * 2);
    ushort* h2 = (ushort*)alloc((size_t)NN * 128 * 2);
    ushort* dummy = (ushort*)alloc((size_t)NN * 128 * 2);  // probe output sink

    hipMemsetAsync(cursor, 0, (size_t)NN * 4, stream);
    EdgeParams P;
    P.pw0 = pw[0]; P.pb0 = pb[0]; P.mu0 = mu[0]; P.is0 = isg[0];
    P.pw1 = pw[1]; P.pb1 = pb[1]; P.mu1 = mu[1]; P.is1 = isg[1];
    P.pw2 = pw[2]; P.pb2 = pb[2]; P.mu2 = mu[2]; P.is2 = isg[2];
    fill_prep<<<2515, 256, 0, stream>>>(dst, src, pseudo, P, cursor, recs, features, fbf,
                                        fc_w[0], fc_w[1], fc_w[2], w2t_0, w2t_1, w2t_2);

    const int GB = NN / 16;  // 1250 blocks, 16 waves each, 1 node/wave

    layer_fused<64, true, false><<<GB, 1024, 0, stream>>>(
        fbf, cursor, recs, 2, w2t_0, bias[0], h1);
    layer_fused<128, true, false><<<GB, 1024, 0, stream>>>(
        h1, cursor, recs, 4, w2t_1, bias[1], h2);
    layer_fused<128, false, false><<<GB, 1024, 0, stream>>>(
        h2, cursor, recs, 6, w2t_2, bias[2], (float*)d_out);

    // PROBE (this round only): sequential-gather clone of layer 2 -> dummy.
    // Identical rec loads / byte counts / dependence chain; only row order differs.
    layer_fused<128, true, true><<<GB, 1024, 0, stream>>>(
        h2, cursor, recs, 4, w2t_1, bias[1], dummy);
}

// Round 10
// 267.346 us; speedup vs baseline: 1.2594x; 1.2594x over previous
//
#include <hip/hip_runtime.h>
#include <hip/hip_bf16.h>
#include <hip/hip_fp16.h>
#include <math.h>

#define NN 20000
#define NE 320000
#define SLOT 64  // padded-CSR slots per node; P(deg>64) ~ 1e-18 at mean 16

typedef __attribute__((ext_vector_type(8))) short bf16x8;
typedef __attribute__((ext_vector_type(4))) float f32x4;

__device__ inline float bf2f_lo(uint v) {
    union { uint i; float f; } c; c.i = v << 16; return c.f;
}
__device__ inline float bf2f_hi(uint v) {
    union { uint i; float f; } c; c.i = v & 0xffff0000u; return c.f;
}
__device__ inline ushort f2bf(float f) {
    __hip_bfloat16 h = __float2bfloat16(f);
    return *reinterpret_cast<ushort*>(&h);
}
__device__ inline uint pack2bf(float a, float b) {
    return (uint)f2bf(a) | ((uint)f2bf(b) << 16);
}
__device__ inline float2 h2f2(uint u) {  // 2 packed halves -> 2 floats
    union { uint i; __half2 h; } c; c.i = u;
    return __half22float2(c.h);
}
__device__ inline ushort f2h(float f) {
    __half h = __float2half_rn(f);
    return *reinterpret_cast<ushort*>(&h);
}

__device__ inline float fast_tanh(float x) {
    x = fminf(fmaxf(x, -9.f), 9.f);
    float e = __expf(2.f * x);
    return 1.f - 2.f / (e + 1.f);
}

struct EdgeParams {
    const float *pw0, *pb0, *mu0, *is0;
    const float *pw1, *pb1, *mu1, *is1;
    const float *pw2, *pb2, *mu2, *is2;
};

__device__ inline void layer_w(float p0, float p1, const float* pw, const float* pb,
                               const float* mu, const float* is, float* out4) {
    float u0 = fast_tanh(p0 * pw[0] + p1 * pw[2] + pb[0]);
    float u1 = fast_tanh(p0 * pw[1] + p1 * pw[3] + pb[1]);
#pragma unroll
    for (int k = 0; k < 4; ++k) {
        float d0 = (u0 - mu[k * 2 + 0]) * is[k * 2 + 0];
        float d1 = (u1 - mu[k * 2 + 1]) * is[k * 2 + 1];
        out4[k] = __expf(-0.5f * (d0 * d0 + d1 * d1));
    }
}

// ---- prep: edge records (blocks 0..1249) + weight transpose (1250..1889)
//      + features->bf16 (1890..2514) ----
// Record: 32B = {src, pad, w0(half4=8B), w1, w2} -> ONE cache line per edge scatter.
__global__ void fill_prep(const int* __restrict__ dst, const int* __restrict__ src,
                          const float* __restrict__ pseudo, EdgeParams P,
                          int* __restrict__ cursor, uint* __restrict__ recs,
                          const float* __restrict__ features, ushort* __restrict__ fbf,
                          const float* __restrict__ f0, const float* __restrict__ f1,
                          const float* __restrict__ f2, ushort* __restrict__ w0,
                          ushort* __restrict__ w1, ushort* __restrict__ w2) {
    int bid = blockIdx.x;
    if (bid < 1250) {
        int e = bid * 256 + threadIdx.x;  // 1250*256 == NE exactly
        int n = dst[e];
        int pos = atomicAdd(&cursor[n], 1);
        if (pos < SLOT) {
            size_t slot = (size_t)n * SLOT + pos;
            float2 p = *(const float2*)(pseudo + (size_t)e * 2);  // contiguous read
            float w[4];
            uint pk0x, pk0y, pk1x, pk1y, pk2x, pk2y;
            layer_w(p.x, p.y, P.pw0, P.pb0, P.mu0, P.is0, w);
            pk0x = (uint)f2h(w[0]) | ((uint)f2h(w[1]) << 16);
            pk0y = (uint)f2h(w[2]) | ((uint)f2h(w[3]) << 16);
            layer_w(p.x, p.y, P.pw1, P.pb1, P.mu1, P.is1, w);
            pk1x = (uint)f2h(w[0]) | ((uint)f2h(w[1]) << 16);
            pk1y = (uint)f2h(w[2]) | ((uint)f2h(w[3]) << 16);
            layer_w(p.x, p.y, P.pw2, P.pb2, P.mu2, P.is2, w);
            pk2x = (uint)f2h(w[0]) | ((uint)f2h(w[1]) << 16);
            pk2y = (uint)f2h(w[2]) | ((uint)f2h(w[3]) << 16);
            uint* r = recs + slot * 8;
            *(uint4*)(r + 0) = make_uint4((uint)src[e], 0u, pk0x, pk0y);
            *(uint4*)(r + 4) = make_uint4(pk1x, pk1y, pk2x, pk2y);
        }
    } else if (bid < 1890) {
        int idx = (bid - 1250) * 256 + threadIdx.x;  // 640 blocks cover 163840 exactly
        const float* srcp;
        ushort* dstp;
        int din, KD, li;
        if (idx < 128 * 256) {
            srcp = f0; dstp = w0; din = 64; KD = 256; li = idx;
        } else if (idx < 128 * 256 + 128 * 512) {
            srcp = f1; dstp = w1; din = 128; KD = 512; li = idx - 128 * 256;
        } else {
            srcp = f2; dstp = w2; din = 128; KD = 512; li = idx - 128 * 256 - 128 * 512;
        }
        int n = li / KD;
        int r = li - n * KD;
        int k = r / din;
        int d = r - k * din;
        dstp[li] = f2bf(srcp[d * 512 + k * 128 + n]);
    } else {
        // features f32 -> bf16: 20000*64 = 1.28M elems, 8 per thread, 625 blocks exact
        int idx = (bid - 1890) * 256 + threadIdx.x;  // < 160000
        size_t b8 = (size_t)idx * 8;
        float4 a = *(const float4*)(features + b8);
        float4 b = *(const float4*)(features + b8 + 4);
        uint4 o;
        o.x = pack2bf(a.x, a.y);
        o.y = pack2bf(a.z, a.w);
        o.z = pack2bf(b.x, b.y);
        o.w = pack2bf(b.z, b.w);
        *(uint4*)(fbf + b8) = o;
    }
}

// ---------------- fused layer: 16 waves/block, ONE node per wave, QUAD-gather ----------------
// One vmem instruction gathers FOUR edges' rows: lane-group g (quad, 16 lanes) reads edge
// i+g's row slice (dwordx4 for DIN=128, dwordx2 for DIN=64). Records on scalar pipe,
// per-group select via cndmask. Cross-group combine: shfl_xor(16) + shfl_xor(32) per node.
template <int DIN, bool OUTBF>
__global__ __launch_bounds__(1024, 4) void layer_fused(
    const ushort* __restrict__ hbf, const int* __restrict__ cursor,
    const uint* __restrict__ recs, int woff,
    const ushort* __restrict__ Bt, const float* __restrict__ bias,
    void* __restrict__ hout) {
    constexpr int KD = 4 * DIN;
    constexpr int PITCH = KD + 8;   // ushorts; 16B-aligned rows
    constexpr int FPL = DIN / 16;   // features per lane: 8 (DIN=128) or 4 (DIN=64)
    __shared__ __align__(16) ushort Ts[16 * PITCH];
    int wv = threadIdx.x >> 6, lane = threadIdx.x & 63;
    int l16 = lane & 15, quad = lane >> 4;
    int nb = blockIdx.x * 16;
    int n = nb + wv;

    int deg = __builtin_amdgcn_readfirstlane(cursor[n]);
    deg = deg < SLOT ? deg : SLOT;  // safety clamp
    size_t base = (size_t)n * SLOT;

    float acc[4 * FPL];  // k-major: acc[k*FPL + j]
#pragma unroll
    for (int j = 0; j < 4 * FPL; ++j) acc[j] = 0.f;

    for (int i = 0; i < deg; i += 16) {
        uint4 hv[4];
        float wk[4][4];  // [q][k]
#pragma unroll
        for (int q = 0; q < 4; ++q) {
            int e0 = i + 4 * q;
            uint s_[4], lo_[4], hi_[4];
#pragma unroll
            for (int j = 0; j < 4; ++j) {
                int ee = e0 + j;
                size_t idx = base + (ee < deg ? ee : 0);  // uniform -> s_load
                const uint* r = recs + idx * 8;
                s_[j] = r[0];
                lo_[j] = r[woff];
                hi_[j] = r[woff + 1];
            }
            // per-lane select by quad group
            uint sg = quad < 2 ? (quad == 0 ? s_[0] : s_[1]) : (quad == 2 ? s_[2] : s_[3]);
            uint lg = quad < 2 ? (quad == 0 ? lo_[0] : lo_[1]) : (quad == 2 ? lo_[2] : lo_[3]);
            uint hg = quad < 2 ? (quad == 0 ? hi_[0] : hi_[1]) : (quad == 2 ? hi_[2] : hi_[3]);
            bool ok = (e0 + quad) < deg;
            lg = ok ? lg : 0u;
            hg = ok ? hg : 0u;
            float2 wa = h2f2(lg);
            float2 wb = h2f2(hg);
            wk[q][0] = wa.x; wk[q][1] = wa.y; wk[q][2] = wb.x; wk[q][3] = wb.y;
            const ushort* row = hbf + (size_t)sg * DIN + l16 * FPL;
            if (DIN == 128) {
                hv[q] = *(const uint4*)row;
            } else {
                uint2 t = *(const uint2*)row;
                hv[q].x = t.x; hv[q].y = t.y; hv[q].z = 0u; hv[q].w = 0u;
            }
        }
#pragma unroll
        for (int q = 0; q < 4; ++q) {
            float f[FPL];
            f[0] = bf2f_lo(hv[q].x); f[1] = bf2f_hi(hv[q].x);
            f[2] = bf2f_lo(hv[q].y); f[3] = bf2f_hi(hv[q].y);
            if (DIN == 128) {
                f[4] = bf2f_lo(hv[q].z); f[5] = bf2f_hi(hv[q].z);
                f[6] = bf2f_lo(hv[q].w); f[7] = bf2f_hi(hv[q].w);
            }
#pragma unroll
            for (int k = 0; k < 4; ++k)
#pragma unroll
                for (int j = 0; j < FPL; ++j)
                    acc[k * FPL + j] += wk[q][k] * f[j];
        }
    }
    // cross-group combine: groups differ in lane bits 4,5
#pragma unroll
    for (int j = 0; j < 4 * FPL; ++j) {
        acc[j] += __shfl_xor(acc[j], 16);
        acc[j] += __shfl_xor(acc[j], 32);
    }
    if (lane < 16) {
#pragma unroll
        for (int k = 0; k < 4; ++k) {
            if (DIN == 128) {
                ushort p[8];
#pragma unroll
                for (int j = 0; j < 8; ++j) p[j] = f2bf(acc[k * 8 + j]);
                *(bf16x8*)(Ts + wv * PITCH + k * DIN + l16 * 8) = *(const bf16x8*)p;
            } else {
                ushort4 p;
                p.x = f2bf(acc[k * 4 + 0]);
                p.y = f2bf(acc[k * 4 + 1]);
                p.z = f2bf(acc[k * 4 + 2]);
                p.w = f2bf(acc[k * 4 + 3]);
                *(ushort4*)(Ts + wv * PITCH + k * DIN + l16 * 4) = p;
            }
        }
    }
    __syncthreads();

    // ---- GEMM phase: waves 0..7, each 16 rows x 16 cols ----
    if (wv < 8) {
        int c0 = wv * 16;
        f32x4 acc2 = (f32x4){0.f, 0.f, 0.f, 0.f};
#pragma unroll 4
        for (int k0 = 0; k0 < KD; k0 += 32) {
            bf16x8 af = *(const bf16x8*)(Ts + l16 * PITCH + k0 + quad * 8);
            bf16x8 bfr = *(const bf16x8*)(Bt + (size_t)(c0 + l16) * KD + k0 + quad * 8);
            acc2 = __builtin_amdgcn_mfma_f32_16x16x32_bf16(af, bfr, acc2, 0, 0, 0);
        }
        int gn = c0 + l16;
        float bv = bias[gn];
#pragma unroll
        for (int i = 0; i < 4; ++i) {
            int gm = nb + quad * 4 + i;
            float val = acc2[i] + bv;
            if (OUTBF)
                ((ushort*)hout)[(size_t)gm * 128 + gn] = f2bf(val);
            else
                ((float*)hout)[(size_t)gm * 128 + gn] = val;
        }
    }
}

extern "C" void kernel_launch(void* const* d_in, const int* in_sizes, int n_in,
                              void* d_out, int out_size, void* d_ws, size_t ws_size,
                              hipStream_t stream) {
    const float* features = (const float*)d_in[0];
    const float* pseudo = (const float*)d_in[1];
    const int* src = (const int*)d_in[2];
    const int* dst = (const int*)d_in[3];
    const float* fc_w[3] = {(const float*)d_in[4], (const float*)d_in[10], (const float*)d_in[16]};
    const float* mu[3] = {(const float*)d_in[5], (const float*)d_in[11], (const float*)d_in[17]};
    const float* isg[3] = {(const float*)d_in[6], (const float*)d_in[12], (const float*)d_in[18]};
    const float* bias[3] = {(const float*)d_in[7], (const float*)d_in[13], (const float*)d_in[19]};
    const float* pw[3] = {(const float*)d_in[8], (const float*)d_in[14], (const float*)d_in[20]};
    const float* pb[3] = {(const float*)d_in[9], (const float*)d_in[15], (const float*)d_in[21]};

    char* ws = (char*)d_ws;
    auto alloc = [&](size_t bytes) -> void* {
        void* p = (void*)ws;
        ws += (bytes + 255) & ~(size_t)255;
        return p;
    };
    int* cursor = (int*)alloc((size_t)NN * 4);
    uint* recs = (uint*)alloc((size_t)NN * SLOT * 32);   // 32B record per slot
    ushort* fbf = (ushort*)alloc((size_t)NN * 64 * 2);   // features in bf16
    ushort* w2t_0 = (ushort*)alloc((size_t)128 * 256 * 2);
    ushort* w2t_1 = (ushort*)alloc((size_t)128 * 512 * 2);
    ushort* w2t_2 = (ushort*)alloc((size_t)128 * 512 * 2);
    ushort* h1 = (ushort*)alloc((size_t)NN * 128 * 2);
    ushort* h2 = (ushort*)alloc((size_t)NN * 128 * 2);

    hipMemsetAsync(cursor, 0, (size_t)NN * 4, stream);
    EdgeParams P;
    P.pw0 = pw[0]; P.pb0 = pb[0]; P.mu0 = mu[0]; P.is0 = isg[0];
    P.pw1 = pw[1]; P.pb1 = pb[1]; P.mu1 = mu[1]; P.is1 = isg[1];
    P.pw2 = pw[2]; P.pb2 = pb[2]; P.mu2 = mu[2]; P.is2 = isg[2];
    fill_prep<<<2515, 256, 0, stream>>>(dst, src, pseudo, P, cursor, recs, features, fbf,
                                        fc_w[0], fc_w[1], fc_w[2], w2t_0, w2t_1, w2t_2);

    const int GB = NN / 16;  // 1250 blocks, 16 waves each, 1 node/wave

    layer_fused<64, true><<<GB, 1024, 0, stream>>>(
        fbf, cursor, recs, 2, w2t_0, bias[0], h1);
    layer_fused<128, true><<<GB, 1024, 0, stream>>>(
        h1, cursor, recs, 4, w2t_1, bias[1], h2);
    layer_fused<128, false><<<GB, 1024, 0, stream>>>(
        h2, cursor, recs, 6, w2t_2, bias[2], (float*)d_out);
}